// Round 1
// baseline (822.838 us; speedup 1.0000x reference)
//
#include <hip/hip_runtime.h>
#include <hip/hip_bf16.h>
#include <math.h>

// ModelParallelSoftmaxLoss: loss = mean(logsumexp(x@W^T + b) - (x@W^T+b)[lb])
// N=4096, D=512, V=100000.
// R7: fix rule-#20 violation in R6 — Aa[2][4] was indexed by runtime ks=u&3
//     (VGPR_Count=88 proved A-fragments were NOT register-resident; VALUBusy 40%).
//     (a) tile loop with all 4 K-steps unrolled: Aa index, LDS buffer index and
//         stage offsets all compile-time -> A truly lives in 64 VGPRs.
//     (b) x quantized pre-scaled by log2(e): epilogue uses raw v_exp_f32 (exp2),
//         saving 64 v_mul per tile-group; bias scaled by log2e at load.
//     (c) first K-step of each tile issues MFMA with C=0 (template) -> no 64-reg
//         acc re-zero pass per tile.
//     (d) bias loads hoisted to tile start (12 staging loads issued between load
//         and use -> compiler emits counted vmcnt, not a drain).
//     Sync structure (2-buffer, one __syncthreads per K-step) is UNCHANGED from
//     the verified R6 kernel.

#define N_ROWS 4096
#define DIM    512              // elements per row == bytes per row in fp8
#define VOCAB  100000
#define NTILES 782              // ceil(100000/128)
#define VPAD   (NTILES * 128)   // 100096
#define SPLITS 32
#define TPS    25               // ceil(782/32)
#define XELEMS (N_ROWS * DIM)           // 2097152
#define WVALID ((size_t)VOCAB * DIM)    // 51200000
#define WBYTES ((size_t)VPAD * DIM)     // 51249152

#define LOG2E 1.44269504088896340736f

typedef __attribute__((ext_vector_type(4))) int   i32x4;
typedef __attribute__((ext_vector_type(8))) int   i32x8;
typedef __attribute__((ext_vector_type(4))) float f32x4;

// ---------------- helpers ----------------

__device__ __forceinline__ void gload_lds16(const char* g, char* l) {
  // async global->LDS, 16B/lane; LDS dest = wave-uniform base + lane*16
  __builtin_amdgcn_global_load_lds(
      (const __attribute__((address_space(1))) unsigned int*)g,
      (__attribute__((address_space(3))) unsigned int*)l, 16, 0, 0);
}

__device__ __forceinline__ int pack4_fp8(float4 f, float sc) {
  int p = __builtin_amdgcn_cvt_pk_fp8_f32(f.x * sc, f.y * sc, 0, false);
  p = __builtin_amdgcn_cvt_pk_fp8_f32(f.z * sc, f.w * sc, p, true);
  return p;
}

// read one 32B fragment stored fragment-order: lo at base, hi at base+1024
__device__ __forceinline__ i32x8 frag32(const char* base) {
  i32x4 lo = *(const i32x4*)(base);
  i32x4 hi = *(const i32x4*)(base + 1024);
  return (i32x8){lo.x, lo.y, lo.z, lo.w, hi.x, hi.y, hi.z, hi.w};
}

// 16 MFMAs of one K-step; FIRST -> accumulate onto C=0 (no acc pre-zero needed)
template <bool FIRST>
__device__ __forceinline__ void mfma_step(const i32x8 a0, const i32x8 a1,
                                          const char* fB, f32x4 acc[2][8]) {
#pragma unroll
  for (int j = 0; j < 8; ++j) {
    const i32x8 bf = frag32(fB + j * 2048);
    acc[0][j] = __builtin_amdgcn_mfma_scale_f32_16x16x128_f8f6f4(
        a0, bf, FIRST ? (f32x4){0.f, 0.f, 0.f, 0.f} : acc[0][j], 0, 0, 0, 127, 0, 122);
    acc[1][j] = __builtin_amdgcn_mfma_scale_f32_16x16x128_f8f6f4(
        a1, bf, FIRST ? (f32x4){0.f, 0.f, 0.f, 0.f} : acc[1][j], 0, 0, 0, 127, 0, 122);
  }
}

// ---------------- fused conversion: x (scale log2e) and W (value*32, MX scale 2^-5) -> fp8 ----------------

__global__ __launch_bounds__(256) void cvt_kernel(const float* __restrict__ x,
                                                  const float* __restrict__ W,
                                                  char* __restrict__ out8) {
  const size_t e = ((size_t)blockIdx.x * 256 + threadIdx.x) * 16;  // grid 13024: exact
  int4 o;
  if (e < (size_t)XELEMS) {
    // x pre-scaled by log2(e): GEMM then yields logits*log2e, so the sum-exp
    // epilogue is a raw v_exp_f32 (base-2) with no per-element multiply.
    const float4* s = (const float4*)(x + e);
    o.x = pack4_fp8(s[0], LOG2E); o.y = pack4_fp8(s[1], LOG2E);
    o.z = pack4_fp8(s[2], LOG2E); o.w = pack4_fp8(s[3], LOG2E);
  } else if (e - XELEMS < WVALID) {
    const float4* s = (const float4*)(W + (e - XELEMS));
    o.x = pack4_fp8(s[0], 32.f); o.y = pack4_fp8(s[1], 32.f);
    o.z = pack4_fp8(s[2], 32.f); o.w = pack4_fp8(s[3], 32.f);
  } else {
    o.x = 0; o.y = 0; o.z = 0; o.w = 0;   // vocab pad rows (also masked via badd=-inf)
  }
  *(int4*)(out8 + e) = o;
}

// ---------------- exact fp32 target logit: tgt[r] = x[r] . W[lb[r]] + b[lb[r]] ----------------

__global__ __launch_bounds__(256) void tgt_kernel(const float* __restrict__ x,
                                                  const int* __restrict__ lb,
                                                  const float* __restrict__ W,
                                                  const float* __restrict__ bias,
                                                  float* __restrict__ tgt) {
  const int wv = threadIdx.x >> 6;
  const int lane = threadIdx.x & 63;
  const int row = blockIdx.x * 4 + wv;   // grid 1024 -> 4096 rows exact
  const int t = lb[row];
  const float* xr = x + (size_t)row * DIM;
  const float* wr = W + (size_t)t * DIM;
  float s = 0.f;
#pragma unroll
  for (int i = 0; i < 8; ++i) s += xr[lane + i * 64] * wr[lane + i * 64];
#pragma unroll
  for (int m = 32; m; m >>= 1) s += __shfl_xor(s, m);
  if (lane == 0) tgt[row] = s + bias[t];
}

// ---------------- fused MX-fp8 GEMM + sum-exp ----------------
// grid: 1024 = 32 m-tiles x 32 V-splits. block: 4 waves; wave w owns rows m0+32w..+31
// as 2 row-frags x 8 col-frags of 16x16x128 (K=128, 4 K-steps over D=512).
// A frag (held in regs): lane(fr,fq) = row fr, k-bytes fq*32..+31 of each 128B K-window.
// B LDS (per buffer, 16KB): 8 col-groups of 16 rows; group g at g*2048; slot =
// half*1024 + lane*16 holds row 16g+fr, k-bytes fq*32+half*16..+15.
// Scales: A identity (e8m0 127) — log2e is folded into x's fp8 values;
//         B 2^-5 (122) undoing the W*32 quantization scale.

__global__ __launch_bounds__(256, 1) void lse_kernel(const char* __restrict__ xb,
                                                     const char* __restrict__ wb,
                                                     const float* __restrict__ bias,
                                                     float* __restrict__ spart) {
  __shared__ __align__(16) char ldsB[2][16384];

  const int bI = blockIdx.x;
  const int mtile = bI >> 5;
  const int s = bI & 31;
  const int m0 = mtile * 128;
  const int t0 = s * TPS;
  const int t1 = (t0 + TPS < NTILES) ? (t0 + TPS) : NTILES;

  const int tid  = threadIdx.x;
  const int lane = tid & 63;
  const int wv   = tid >> 6;
  const int fr   = lane & 15;        // frag row (A) / col (B,C); staging row-in-group
  const int fq   = lane >> 4;        // frag quad; staging k-chunk

  // ---- load A fragments into registers (64 VGPRs) ----
  i32x8 Aa[2][4];
  {
    const char* ax = xb + (size_t)(m0 + 32 * wv + fr) * DIM + fq * 32;
#pragma unroll
    for (int i = 0; i < 2; ++i)
#pragma unroll
      for (int ks = 0; ks < 4; ++ks) {
        const char* p = ax + i * (16 * DIM) + ks * 128;
        i32x4 lo = *(const i32x4*)p;
        i32x4 hi = *(const i32x4*)(p + 16);
        Aa[i][ks] = (i32x8){lo.x, lo.y, lo.z, lo.w, hi.x, hi.y, hi.z, hi.w};
      }
  }

  // per-wave B staging: groups 2wv, 2wv+1 (4 calls of 1KB per K-step)
  const size_t bRowOff = (size_t)(32 * wv + fr) * DIM + fq * 32;
  char* const dB0 = &ldsB[0][wv * 4096];
  char* const dB1 = &ldsB[1][wv * 4096];

  auto stageB = [&](const char* src, char* d) {
    gload_lds16(src,                d);           // group 2wv,   half 0
    gload_lds16(src + 16,           d + 1024);    // group 2wv,   half 1
    gload_lds16(src + 16 * DIM,     d + 2048);    // group 2wv+1, half 0
    gload_lds16(src + 16 * DIM + 16, d + 3072);   // group 2wv+1, half 1
  };

  float S[2][4];
#pragma unroll
  for (int i = 0; i < 2; ++i)
#pragma unroll
    for (int r = 0; r < 4; ++r) S[i][r] = 0.f;

  f32x4 acc[2][8];   // written with C=0 at ks0 of each tile; no pre-zero needed

  const char* fB0 = &ldsB[0][lane * 16];
  const char* fB1 = &ldsB[1][lane * 16];

  const char* wt = wb + (size_t)t0 * (128 * DIM) + bRowOff;
  stageB(wt, dB0);
  __syncthreads();   // buf0 ready (vmcnt drain + barrier)

  for (int tt = t0; tt < t1; ++tt, wt += 128 * DIM) {
    // bias for this tile, pre-scaled by log2e; issued early so the compiler's
    // wait before use is counted (12 staging loads in between), not a drain.
    const int v0t = tt * 128;
    float badd[8];
#pragma unroll
    for (int j = 0; j < 8; ++j) {
      const int col = v0t + 16 * j + fr;
      badd[j] = (col < VOCAB) ? bias[col] * LOG2E : -INFINITY;  // exp2(-inf)=0 masks tail
    }

    // ks=0 (buf0); stage ks=1 -> buf1
    stageB(wt + 128, dB1);
    mfma_step<true>(Aa[0][0], Aa[1][0], fB0, acc);
    __syncthreads();

    // ks=1 (buf1); stage ks=2 -> buf0
    stageB(wt + 256, dB0);
    mfma_step<false>(Aa[0][1], Aa[1][1], fB1, acc);
    __syncthreads();

    // ks=2 (buf0); stage ks=3 -> buf1
    stageB(wt + 384, dB1);
    mfma_step<false>(Aa[0][2], Aa[1][2], fB0, acc);
    __syncthreads();

    // ks=3 (buf1); stage next tile ks=0 -> buf0 (epilogue overlaps its latency)
    if (tt + 1 < t1) stageB(wt + 128 * DIM, dB0);
    mfma_step<false>(Aa[0][3], Aa[1][3], fB1, acc);

    // epilogue: C/D (16x16): col = v0t+16j+fr, row = m0+32wv+16i+4fq+r
    // logits arrive pre-scaled by log2e -> raw exp2, no multiply.
#pragma unroll
    for (int i = 0; i < 2; ++i)
#pragma unroll
      for (int r = 0; r < 4; ++r) {
        float sum = 0.f;
#pragma unroll
        for (int j = 0; j < 8; ++j)
          sum += __builtin_amdgcn_exp2f(acc[i][j][r] + badd[j]);
        S[i][r] += sum;
      }

    __syncthreads();   // drains ks3 staging vmcnt (next-tile buf0 ready) + protects buf1
  }

  // reduce over the 16 lanes sharing each row group, write partials
#pragma unroll
  for (int i = 0; i < 2; ++i)
#pragma unroll
    for (int r = 0; r < 4; ++r) {
      float v = S[i][r];
      v += __shfl_xor(v, 1);
      v += __shfl_xor(v, 2);
      v += __shfl_xor(v, 4);
      v += __shfl_xor(v, 8);
      if (fr == 0) {
        const int row = m0 + 32 * wv + 16 * i + 4 * fq + r;
        spart[(size_t)row * SPLITS + s] = v;
      }
    }
}

// ---------------- combine: loss = mean(log(sum_s S_part) - tgt), single block ----------------

__global__ __launch_bounds__(256) void combine_kernel(const float* __restrict__ spart,
                                                      const float* __restrict__ tgt,
                                                      float* __restrict__ out) {
  __shared__ float red[256];
  float local = 0.f;
  for (int r = threadIdx.x; r < N_ROWS; r += 256) {
    const float4* sp = (const float4*)(spart + (size_t)r * SPLITS);
    float st = 0.f;
#pragma unroll
    for (int i = 0; i < 8; ++i) { float4 v = sp[i]; st += (v.x + v.y) + (v.z + v.w); }
    local += __logf(st) - tgt[r];
  }
  red[threadIdx.x] = local;
  __syncthreads();
  for (int step = 128; step; step >>= 1) {
    if (threadIdx.x < step) red[threadIdx.x] += red[threadIdx.x + step];
    __syncthreads();
  }
  if (threadIdx.x == 0) out[0] = red[0] * (1.0f / (float)N_ROWS);
}

// ---------------- launch ----------------
// ws: x_fp8 [4096][512]B @0 | W_fp8 [100096][512]B | S_part [4096][32] f32 | tgt [4096] f32

extern "C" void kernel_launch(void* const* d_in, const int* in_sizes, int n_in,
                              void* d_out, int out_size, void* d_ws, size_t ws_size,
                              hipStream_t stream) {
  const float* x  = (const float*)d_in[0];
  const int*   lb = (const int*)d_in[1];
  const float* W  = (const float*)d_in[2];
  const float* b  = (const float*)d_in[3];
  float* out = (float*)d_out;

  char* ws = (char*)d_ws;
  const size_t OFF_W   = (size_t)XELEMS;          // 2097152
  const size_t OFF_SP  = OFF_W + WBYTES;          // 53346304
  const size_t OFF_TGT = OFF_SP + (size_t)N_ROWS * SPLITS * 4;
  char*  xb    = ws;
  char*  wb    = ws + OFF_W;
  float* spart = (float*)(ws + OFF_SP);
  float* tgt   = (float*)(ws + OFF_TGT);

  cvt_kernel<<<13024, 256, 0, stream>>>(x, W, ws);
  tgt_kernel<<<1024, 256, 0, stream>>>(x, lb, W, b, tgt);
  lse_kernel<<<1024, 256, 0, stream>>>(xb, wb, b, spart);
  combine_kernel<<<1, 256, 0, stream>>>(spart, tgt, out);
}

// Round 2
// 586.329 us; speedup vs baseline: 1.4034x; 1.4034x over previous
//
#include <hip/hip_runtime.h>
#include <hip/hip_bf16.h>
#include <math.h>

// ModelParallelSoftmaxLoss: loss = mean(logsumexp(x@W^T + b) - (x@W^T+b)[lb])
// N=4096, D=512, V=100000.
// R8: counted-vmcnt pipeline (T3+T4). R7 was latency-bound: every __syncthreads
//     drained vmcnt(0) -> per-K-step stage latency fully exposed at 1 block/CU
//     (MfmaUtil 16% = exact compute floor, 84% idle).
//     (a) 4 LDS buffers (64KB), prefetch depth 3: stage(u+3) issued per step,
//         s_waitcnt vmcnt(8) before each raw s_barrier — never 0 in main loop.
//         Tail peeled with waits 8,8,4,0 (those loads are 3 steps old -> free).
//     (b) raw __builtin_amdgcn_s_barrier + sched_barrier(0) (no fence drain);
//         race analysis: RAW = own vmcnt(8) + barrier; WAR = stage(u+3) writes
//         buf[(u-1)&3] only after the barrier all waves reach with step-(u-1)
//         ds_reads retired (lgkm is in-order before their MFMAs).
//     (c) bias staged to LDS at entry (12.8KB) so no global loads pollute the
//         vmcnt count inside the loop; pre-scaled by log2e, -inf tail mask.
//     (d) s_setprio(1) around MFMA clusters (T5: phase structure now exists).
//     (e) bijective XCD swizzle: each XCD's resident blocks share 2 splits ->
//         2 x 1.6MB W slices fit the 4MB per-XCD L2 (staging needs ~18 TB/s,
//         more than L3 alone sustains).

#define N_ROWS 4096
#define DIM    512              // elements per row == bytes per row in fp8
#define VOCAB  100000
#define NTILES 782              // ceil(100000/128)
#define VPAD   (NTILES * 128)   // 100096
#define SPLITS 32
#define TPS    25               // ceil(782/32)
#define XELEMS (N_ROWS * DIM)           // 2097152
#define WVALID ((size_t)VOCAB * DIM)    // 51200000
#define WBYTES ((size_t)VPAD * DIM)     // 51249152
#define TILEB  (128 * DIM)              // 65536 B: one 128-col V-tile of W(fp8)

#define LOG2E 1.44269504088896340736f

typedef __attribute__((ext_vector_type(4))) int   i32x4;
typedef __attribute__((ext_vector_type(8))) int   i32x8;
typedef __attribute__((ext_vector_type(4))) float f32x4;

// counted wait: literal N so the HW vmcnt math stays exact; memory clobber pins
// all memory ops (stages can't hoist above, ds_reads can't sink below).
#define WAITV(n) asm volatile("s_waitcnt vmcnt(" #n ")" ::: "memory")
// raw barrier (no vmcnt drain) + full scheduling fence so ds_reads of the
// freshly-ready buffer cannot be hoisted above the rendezvous (rule #18).
#define BARRIER_PIN()                         \
  do {                                        \
    __builtin_amdgcn_s_barrier();             \
    __builtin_amdgcn_sched_barrier(0);        \
  } while (0)

// ---------------- helpers ----------------

__device__ __forceinline__ void gload_lds16(const char* g, char* l) {
  // async global->LDS, 16B/lane; LDS dest = wave-uniform base + lane*16
  __builtin_amdgcn_global_load_lds(
      (const __attribute__((address_space(1))) unsigned int*)g,
      (__attribute__((address_space(3))) unsigned int*)l, 16, 0, 0);
}

__device__ __forceinline__ int pack4_fp8(float4 f, float sc) {
  int p = __builtin_amdgcn_cvt_pk_fp8_f32(f.x * sc, f.y * sc, 0, false);
  p = __builtin_amdgcn_cvt_pk_fp8_f32(f.z * sc, f.w * sc, p, true);
  return p;
}

// read one 32B fragment stored fragment-order: lo at base, hi at base+1024
__device__ __forceinline__ i32x8 frag32(const char* base) {
  i32x4 lo = *(const i32x4*)(base);
  i32x4 hi = *(const i32x4*)(base + 1024);
  return (i32x8){lo.x, lo.y, lo.z, lo.w, hi.x, hi.y, hi.z, hi.w};
}

// 16 MFMAs of one K-step; FIRST -> accumulate onto C=0 (no acc pre-zero needed)
template <bool FIRST>
__device__ __forceinline__ void mfma_step(const i32x8 a0, const i32x8 a1,
                                          const char* fB, f32x4 acc[2][8]) {
  __builtin_amdgcn_s_setprio(1);
#pragma unroll
  for (int j = 0; j < 8; ++j) {
    const i32x8 bf = frag32(fB + j * 2048);
    acc[0][j] = __builtin_amdgcn_mfma_scale_f32_16x16x128_f8f6f4(
        a0, bf, FIRST ? (f32x4){0.f, 0.f, 0.f, 0.f} : acc[0][j], 0, 0, 0, 127, 0, 122);
    acc[1][j] = __builtin_amdgcn_mfma_scale_f32_16x16x128_f8f6f4(
        a1, bf, FIRST ? (f32x4){0.f, 0.f, 0.f, 0.f} : acc[1][j], 0, 0, 0, 127, 0, 122);
  }
  __builtin_amdgcn_s_setprio(0);
}

// ---------------- fused conversion: x (scale log2e) and W (value*32, MX scale 2^-5) -> fp8 ----------------

__global__ __launch_bounds__(256) void cvt_kernel(const float* __restrict__ x,
                                                  const float* __restrict__ W,
                                                  char* __restrict__ out8) {
  const size_t e = ((size_t)blockIdx.x * 256 + threadIdx.x) * 16;  // grid 13024: exact
  int4 o;
  if (e < (size_t)XELEMS) {
    // x pre-scaled by log2(e): GEMM yields logits*log2e -> epilogue is raw exp2.
    const float4* s = (const float4*)(x + e);
    o.x = pack4_fp8(s[0], LOG2E); o.y = pack4_fp8(s[1], LOG2E);
    o.z = pack4_fp8(s[2], LOG2E); o.w = pack4_fp8(s[3], LOG2E);
  } else if (e - XELEMS < WVALID) {
    const float4* s = (const float4*)(W + (e - XELEMS));
    o.x = pack4_fp8(s[0], 32.f); o.y = pack4_fp8(s[1], 32.f);
    o.z = pack4_fp8(s[2], 32.f); o.w = pack4_fp8(s[3], 32.f);
  } else {
    o.x = 0; o.y = 0; o.z = 0; o.w = 0;   // vocab pad rows (also masked via badd=-inf)
  }
  *(int4*)(out8 + e) = o;
}

// ---------------- exact fp32 target logit: tgt[r] = x[r] . W[lb[r]] + b[lb[r]] ----------------

__global__ __launch_bounds__(256) void tgt_kernel(const float* __restrict__ x,
                                                  const int* __restrict__ lb,
                                                  const float* __restrict__ W,
                                                  const float* __restrict__ bias,
                                                  float* __restrict__ tgt) {
  const int wv = threadIdx.x >> 6;
  const int lane = threadIdx.x & 63;
  const int row = blockIdx.x * 4 + wv;   // grid 1024 -> 4096 rows exact
  const int t = lb[row];
  const float* xr = x + (size_t)row * DIM;
  const float* wr = W + (size_t)t * DIM;
  float s = 0.f;
#pragma unroll
  for (int i = 0; i < 8; ++i) s += xr[lane + i * 64] * wr[lane + i * 64];
#pragma unroll
  for (int m = 32; m; m >>= 1) s += __shfl_xor(s, m);
  if (lane == 0) tgt[row] = s + bias[t];
}

// ---------------- fused MX-fp8 GEMM + sum-exp ----------------
// grid: 1024 = 32 m-tiles x 32 V-splits. block: 4 waves; wave w owns rows m0+32w..+31
// as 2 row-frags x 8 col-frags of 16x16x128 (K=128, 4 K-steps over D=512).
// A frag (held in regs): lane(fr,fq) = row fr, k-bytes fq*32..+31 of each 128B K-window.
// B LDS (per buffer, 16KB): 8 col-groups of 16 rows; group g at g*2048; slot =
// half*1024 + lane*16 holds row 16g+fr, k-bytes fq*32+half*16..+15.
// Scales: A identity (e8m0 127) — log2e folded into x fp8; B 2^-5 (122).
// Pipeline: buffers 0..3 = K-steps (u&3); prologue stages steps 0,1,2; per step:
//   WAITV(8) [stage u landed: u+1,u+2 may remain = 8 loads] -> s_barrier ->
//   stage(u+3) -> ds_read buf[u&3] + 16 MFMA.  Last tile: waits 8,8,4,0.

__global__ __launch_bounds__(256, 2) void lse_kernel(const char* __restrict__ xb,
                                                     const char* __restrict__ wb,
                                                     const float* __restrict__ bias,
                                                     float* __restrict__ spart) {
  __shared__ __align__(16) char ldsB[4][16384];   // 64KB B double^2-buffer
  __shared__ float ldsBias[TPS * 128];            // 12.8KB bias (log2e-scaled)

  // Bijective XCD swizzle: HW round-robins dispatch id across 8 XCDs; with
  // this map, one XCD's co-resident blocks (2 blocks/CU x 32 CU) cover
  // splits {2x,2x+1} x all 32 m-tiles -> their W slices (3.2MB) fit 4MB L2.
  const int d = blockIdx.x;
  const int s     = 2 * (d & 7) + ((d >> 3) & 1) + 16 * (d >> 9);
  const int mtile = (d >> 4) & 31;

  const int m0 = mtile * 128;
  const int t0 = s * TPS;
  const int t1 = (t0 + TPS < NTILES) ? (t0 + TPS) : NTILES;
  const int NT = t1 - t0;                 // 25, or 7 on the last split

  const int tid  = threadIdx.x;
  const int lane = tid & 63;
  const int wv   = tid >> 6;
  const int fr   = lane & 15;        // frag row (A) / col (B,C); staging row-in-group
  const int fq   = lane >> 4;        // frag quad; staging k-chunk

  // ---- load A fragments into registers (64 VGPRs) ----
  i32x8 Aa[2][4];
  {
    const char* ax = xb + (size_t)(m0 + 32 * wv + fr) * DIM + fq * 32;
#pragma unroll
    for (int i = 0; i < 2; ++i)
#pragma unroll
      for (int ks = 0; ks < 4; ++ks) {
        const char* p = ax + i * (16 * DIM) + ks * 128;
        i32x4 lo = *(const i32x4*)p;
        i32x4 hi = *(const i32x4*)(p + 16);
        Aa[i][ks] = (i32x8){lo.x, lo.y, lo.z, lo.w, hi.x, hi.y, hi.z, hi.w};
      }
  }

  // ---- stage this split's bias into LDS (keeps loop vmcnt = stages only) ----
  for (int c = tid; c < NT * 128; c += 256) {
    const int col = t0 * 128 + c;
    ldsBias[c] = (col < VOCAB) ? bias[col] * LOG2E : -INFINITY;
  }
  __syncthreads();                        // bias visible; drains ALL vmcnt/lgkm
  asm volatile("s_waitcnt vmcnt(0)" ::: "memory");  // counted-math clean slate
  __builtin_amdgcn_sched_barrier(0);

  // per-wave B staging: groups 2wv, 2wv+1 (4 gload_lds of 1KB per K-step)
  const size_t bRowOff = (size_t)(32 * wv + fr) * DIM + fq * 32;
  char* const dB0 = &ldsB[0][wv * 4096];
  char* const dB1 = &ldsB[1][wv * 4096];
  char* const dB2 = &ldsB[2][wv * 4096];
  char* const dB3 = &ldsB[3][wv * 4096];

  auto stageB = [&](const char* src, char* dst) {
    gload_lds16(src,                 dst);           // group 2wv,   half 0
    gload_lds16(src + 16,            dst + 1024);    // group 2wv,   half 1
    gload_lds16(src + 16 * DIM,      dst + 2048);    // group 2wv+1, half 0
    gload_lds16(src + 16 * DIM + 16, dst + 3072);    // group 2wv+1, half 1
  };

  float S[2][4];
#pragma unroll
  for (int i = 0; i < 2; ++i)
#pragma unroll
    for (int r = 0; r < 4; ++r) S[i][r] = 0.f;

  f32x4 acc[2][8];   // written with C=0 at ks0 of each tile; no pre-zero needed

  const char* fB0 = &ldsB[0][lane * 16];
  const char* fB1 = &ldsB[1][lane * 16];
  const char* fB2 = &ldsB[2][lane * 16];
  const char* fB3 = &ldsB[3][lane * 16];

  auto epilogue = [&](int ti) {
    // C/D (16x16): col = (t0+ti)*128 + 16j + fr, row = m0+32wv+16i+4fq+r.
    // logits pre-scaled by log2e -> raw exp2; bias from LDS (lgkm, not vmcnt).
    const float* bT = &ldsBias[ti * 128];
    float badd[8];
#pragma unroll
    for (int j = 0; j < 8; ++j) badd[j] = bT[16 * j + fr];
#pragma unroll
    for (int i = 0; i < 2; ++i)
#pragma unroll
      for (int r = 0; r < 4; ++r) {
        float sum = 0.f;
#pragma unroll
        for (int j = 0; j < 8; ++j)
          sum += __builtin_amdgcn_exp2f(acc[i][j][r] + badd[j]);
        S[i][r] += sum;
      }
  };

  const char* wt = wb + (size_t)t0 * TILEB + bRowOff;

  // prologue: steps 0,1,2 in flight (12 loads)
  stageB(wt,       dB0);
  stageB(wt + 128, dB1);
  stageB(wt + 256, dB2);

  for (int tt = t0; tt < t1 - 1; ++tt, wt += TILEB) {
    // ks0: consume buf0; stage this tile's ks3 -> buf3
    WAITV(8); BARRIER_PIN();
    stageB(wt + 384, dB3);
    mfma_step<true>(Aa[0][0], Aa[1][0], fB0, acc);

    // ks1: consume buf1; stage next tile's ks0 -> buf0
    WAITV(8); BARRIER_PIN();
    stageB(wt + TILEB, dB0);
    mfma_step<false>(Aa[0][1], Aa[1][1], fB1, acc);

    // ks2: consume buf2; stage next tile's ks1 -> buf1
    WAITV(8); BARRIER_PIN();
    stageB(wt + TILEB + 128, dB1);
    mfma_step<false>(Aa[0][2], Aa[1][2], fB2, acc);

    // ks3: consume buf3; stage next tile's ks2 -> buf2
    WAITV(8); BARRIER_PIN();
    stageB(wt + TILEB + 256, dB2);
    mfma_step<false>(Aa[0][3], Aa[1][3], fB3, acc);

    epilogue(tt - t0);   // runs while next tile's stages are in flight
  }

  // ---- last tile (no next-tile stages; waits 8,8,4,0 — all 3 steps old) ----
  {
    WAITV(8); BARRIER_PIN();
    stageB(wt + 384, dB3);
    mfma_step<true>(Aa[0][0], Aa[1][0], fB0, acc);

    WAITV(8); BARRIER_PIN();
    mfma_step<false>(Aa[0][1], Aa[1][1], fB1, acc);

    WAITV(4); BARRIER_PIN();
    mfma_step<false>(Aa[0][2], Aa[1][2], fB2, acc);

    WAITV(0); BARRIER_PIN();
    mfma_step<false>(Aa[0][3], Aa[1][3], fB3, acc);

    epilogue(NT - 1);
  }

  // reduce over the 16 lanes sharing each row group, write partials
#pragma unroll
  for (int i = 0; i < 2; ++i)
#pragma unroll
    for (int r = 0; r < 4; ++r) {
      float v = S[i][r];
      v += __shfl_xor(v, 1);
      v += __shfl_xor(v, 2);
      v += __shfl_xor(v, 4);
      v += __shfl_xor(v, 8);
      if (fr == 0) {
        const int row = m0 + 32 * wv + 16 * i + 4 * fq + r;
        spart[(size_t)row * SPLITS + s] = v;
      }
    }
}

// ---------------- combine: loss = mean(log(sum_s S_part) - tgt), single block ----------------

__global__ __launch_bounds__(256) void combine_kernel(const float* __restrict__ spart,
                                                      const float* __restrict__ tgt,
                                                      float* __restrict__ out) {
  __shared__ float red[256];
  float local = 0.f;
  for (int r = threadIdx.x; r < N_ROWS; r += 256) {
    const float4* sp = (const float4*)(spart + (size_t)r * SPLITS);
    float st = 0.f;
#pragma unroll
    for (int i = 0; i < 8; ++i) { float4 v = sp[i]; st += (v.x + v.y) + (v.z + v.w); }
    local += __logf(st) - tgt[r];
  }
  red[threadIdx.x] = local;
  __syncthreads();
  for (int step = 128; step; step >>= 1) {
    if (threadIdx.x < step) red[threadIdx.x] += red[threadIdx.x + step];
    __syncthreads();
  }
  if (threadIdx.x == 0) out[0] = red[0] * (1.0f / (float)N_ROWS);
}

// ---------------- launch ----------------
// ws: x_fp8 [4096][512]B @0 | W_fp8 [100096][512]B | S_part [4096][32] f32 | tgt [4096] f32

extern "C" void kernel_launch(void* const* d_in, const int* in_sizes, int n_in,
                              void* d_out, int out_size, void* d_ws, size_t ws_size,
                              hipStream_t stream) {
  const float* x  = (const float*)d_in[0];
  const int*   lb = (const int*)d_in[1];
  const float* W  = (const float*)d_in[2];
  const float* b  = (const float*)d_in[3];
  float* out = (float*)d_out;

  char* ws = (char*)d_ws;
  const size_t OFF_W   = (size_t)XELEMS;          // 2097152
  const size_t OFF_SP  = OFF_W + WBYTES;          // 53346304
  const size_t OFF_TGT = OFF_SP + (size_t)N_ROWS * SPLITS * 4;
  char*  xb    = ws;
  char*  wb    = ws + OFF_W;
  float* spart = (float*)(ws + OFF_SP);
  float* tgt   = (float*)(ws + OFF_TGT);

  cvt_kernel<<<13024, 256, 0, stream>>>(x, W, ws);
  tgt_kernel<<<1024, 256, 0, stream>>>(x, lb, W, b, tgt);
  lse_kernel<<<1024, 256, 0, stream>>>(xb, wb, b, spart);
  combine_kernel<<<1, 256, 0, stream>>>(spart, tgt, out);
}

// Round 3
// 557.779 us; speedup vs baseline: 1.4752x; 1.0512x over previous
//
#include <hip/hip_runtime.h>
#include <hip/hip_bf16.h>
#include <math.h>

// ModelParallelSoftmaxLoss: loss = mean(logsumexp(x@W^T + b) - (x@W^T+b)[lb])
// N=4096, D=512, V=100000.
// R9: LDS-traffic + phase-granularity fix. R8 analysis: per-step 3636 cy vs
//     MFMA 1104 + LDS-read 1024-1500 (B-frag reuse only 2) -> LDS floor above
//     MFMA floor, and 16-MFMA steps phase-locked all waves at each barrier.
//     (a) wave split 2 row-halves x 2 col-halves: 4 A row-frags/wave (Aa[4][4],
//         128 VGPR), B-frag reuse 4x -> LDS reads halved (64KB/CU-step).
//     (b) phase = 2 K-steps, 2 x 32KB buffers; stage issued at phase TOP so
//         WAITV(0) at next phase top is ~free (issue-to-wait = full phase
//         ~2200cy >> 900cy HBM latency). Barriers halved (2/tile).
//     (c) cross-wave (col-half) S-reduction once at end via LDS scratch.
//     Same proven barrier separation as R8 for WAR/RAW; setprio + XCD swizzle
//     + bias-in-LDS retained.

#define N_ROWS 4096
#define DIM    512              // elements per row == bytes per row in fp8
#define VOCAB  100000
#define NTILES 782              // ceil(100000/128)
#define VPAD   (NTILES * 128)   // 100096
#define SPLITS 32
#define TPS    25               // ceil(782/32)
#define XELEMS (N_ROWS * DIM)           // 2097152
#define WVALID ((size_t)VOCAB * DIM)    // 51200000
#define WBYTES ((size_t)VPAD * DIM)     // 51249152
#define TILEB  (128 * DIM)              // 65536 B: one 128-col V-tile of W(fp8)

#define LOG2E 1.44269504088896340736f

typedef __attribute__((ext_vector_type(4))) int   i32x4;
typedef __attribute__((ext_vector_type(8))) int   i32x8;
typedef __attribute__((ext_vector_type(4))) float f32x4;

#define WAITV0() asm volatile("s_waitcnt vmcnt(0)" ::: "memory")
#define BARRIER_PIN()                         \
  do {                                        \
    __builtin_amdgcn_s_barrier();             \
    __builtin_amdgcn_sched_barrier(0);        \
  } while (0)

// ---------------- helpers ----------------

__device__ __forceinline__ void gload_lds16(const char* g, char* l) {
  // async global->LDS, 16B/lane; LDS dest = wave-uniform base + lane*16
  __builtin_amdgcn_global_load_lds(
      (const __attribute__((address_space(1))) unsigned int*)g,
      (__attribute__((address_space(3))) unsigned int*)l, 16, 0, 0);
}

__device__ __forceinline__ int pack4_fp8(float4 f, float sc) {
  int p = __builtin_amdgcn_cvt_pk_fp8_f32(f.x * sc, f.y * sc, 0, false);
  p = __builtin_amdgcn_cvt_pk_fp8_f32(f.z * sc, f.w * sc, p, true);
  return p;
}

// read one 32B fragment stored fragment-order: lo at base, hi at base+1024
__device__ __forceinline__ i32x8 frag32(const char* base) {
  i32x4 lo = *(const i32x4*)(base);
  i32x4 hi = *(const i32x4*)(base + 1024);
  return (i32x8){lo.x, lo.y, lo.z, lo.w, hi.x, hi.y, hi.z, hi.w};
}

// ---------------- fused conversion: x (scale log2e) and W (value*32, MX scale 2^-5) -> fp8 ----------------

__global__ __launch_bounds__(256) void cvt_kernel(const float* __restrict__ x,
                                                  const float* __restrict__ W,
                                                  char* __restrict__ out8) {
  const size_t e = ((size_t)blockIdx.x * 256 + threadIdx.x) * 16;  // grid 13024: exact
  int4 o;
  if (e < (size_t)XELEMS) {
    // x pre-scaled by log2(e): GEMM yields logits*log2e -> epilogue is raw exp2.
    const float4* s = (const float4*)(x + e);
    o.x = pack4_fp8(s[0], LOG2E); o.y = pack4_fp8(s[1], LOG2E);
    o.z = pack4_fp8(s[2], LOG2E); o.w = pack4_fp8(s[3], LOG2E);
  } else if (e - XELEMS < WVALID) {
    const float4* s = (const float4*)(W + (e - XELEMS));
    o.x = pack4_fp8(s[0], 32.f); o.y = pack4_fp8(s[1], 32.f);
    o.z = pack4_fp8(s[2], 32.f); o.w = pack4_fp8(s[3], 32.f);
  } else {
    o.x = 0; o.y = 0; o.z = 0; o.w = 0;   // vocab pad rows (also masked via badd=-inf)
  }
  *(int4*)(out8 + e) = o;
}

// ---------------- exact fp32 target logit: tgt[r] = x[r] . W[lb[r]] + b[lb[r]] ----------------

__global__ __launch_bounds__(256) void tgt_kernel(const float* __restrict__ x,
                                                  const int* __restrict__ lb,
                                                  const float* __restrict__ W,
                                                  const float* __restrict__ bias,
                                                  float* __restrict__ tgt) {
  const int wv = threadIdx.x >> 6;
  const int lane = threadIdx.x & 63;
  const int row = blockIdx.x * 4 + wv;   // grid 1024 -> 4096 rows exact
  const int t = lb[row];
  const float* xr = x + (size_t)row * DIM;
  const float* wr = W + (size_t)t * DIM;
  float s = 0.f;
#pragma unroll
  for (int i = 0; i < 8; ++i) s += xr[lane + i * 64] * wr[lane + i * 64];
#pragma unroll
  for (int m = 32; m; m >>= 1) s += __shfl_xor(s, m);
  if (lane == 0) tgt[row] = s + bias[t];
}

// ---------------- fused MX-fp8 GEMM + sum-exp ----------------
// grid: 1024 = 32 m-tiles x 32 V-splits. block: 4 waves = 2 row-halves (rh) x
// 2 col-halves (ch). Wave owns 64 rows (4 frags of 16) x 64 cols (4 groups of
// 16) -> B-frag reuse 4. K=128 MFMA, 4 K-steps over D=512, 2 K-steps/phase.
// A frag (regs, 128 VGPR): lane(fr,fq) = row fr, k-bytes fq*32..+31 per K-window.
// B LDS buffer (32KB = 2 ksteps x 8 groups x 2KB): group g at ks2*16384+g*2048;
// slot half*1024 + lane*16 holds row 16g+fr, k-bytes fq*32+half*16..+15.
// Scales: A identity (127, log2e folded into x fp8); B 2^-5 (122).
// Pipeline: 2 buffers; phase kp uses buf[kp]; at phase top: WAITV(0) [stage
// issued one full phase earlier -> free] -> s_barrier -> stage next phase.

__global__ __launch_bounds__(256, 2) void lse_kernel(const char* __restrict__ xb,
                                                     const char* __restrict__ wb,
                                                     const float* __restrict__ bias,
                                                     float* __restrict__ spart) {
  __shared__ __align__(16) char ldsB[2][32768];   // 64KB, 2-phase double buffer
  __shared__ float ldsBias[TPS * 128];            // 12.8KB bias (log2e-scaled)

  // Bijective XCD swizzle: one XCD's co-resident blocks cover splits {2x,2x+1}
  // x all 32 m-tiles -> W slices (3.2MB) fit the 4MB per-XCD L2.
  const int d = blockIdx.x;
  const int s     = 2 * (d & 7) + ((d >> 3) & 1) + 16 * (d >> 9);
  const int mtile = (d >> 4) & 31;

  const int m0 = mtile * 128;
  const int t0 = s * TPS;
  const int t1 = (t0 + TPS < NTILES) ? (t0 + TPS) : NTILES;
  const int NT = t1 - t0;                 // 25, or 7 on the last split

  const int tid  = threadIdx.x;
  const int lane = tid & 63;
  const int wv   = tid >> 6;
  const int rh   = wv >> 1;          // row-half (64 rows)
  const int ch   = wv & 1;           // col-half (4 of the 8 col-groups)
  const int fr   = lane & 15;        // frag row (A) / col (B,C); staging row-in-group
  const int fq   = lane >> 4;        // frag quad; staging k-chunk

  // ---- load A fragments into registers (128 VGPRs): 4 row-frags x 4 ksteps ----
  i32x8 Aa[4][4];
  {
    const char* ax = xb + (size_t)(m0 + 64 * rh + fr) * DIM + fq * 32;
#pragma unroll
    for (int rf = 0; rf < 4; ++rf)
#pragma unroll
      for (int ks = 0; ks < 4; ++ks) {
        const char* p = ax + rf * (16 * DIM) + ks * 128;
        i32x4 lo = *(const i32x4*)p;
        i32x4 hi = *(const i32x4*)(p + 16);
        Aa[rf][ks] = (i32x8){lo.x, lo.y, lo.z, lo.w, hi.x, hi.y, hi.z, hi.w};
      }
  }

  // ---- stage this split's bias into LDS ----
  for (int c = tid; c < NT * 128; c += 256) {
    const int col = t0 * 128 + c;
    ldsBias[c] = (col < VOCAB) ? bias[col] * LOG2E : -INFINITY;
  }
  __syncthreads();

  // stage one phase (2 ksteps, 32KB): wave stages groups 2wv,2wv+1 both ksteps
  auto stagePhase = [&](const char* tileSrc, int kp, char* buf) {
#pragma unroll
    for (int ks2 = 0; ks2 < 2; ++ks2) {
      const char* s0 = tileSrc + (2 * kp + ks2) * 128 + fq * 32;
#pragma unroll
      for (int gg = 0; gg < 2; ++gg) {
        const int g = 2 * wv + gg;
        const char* src = s0 + (size_t)(16 * g + fr) * DIM;
        char* dst = buf + ks2 * 16384 + g * 2048;
        gload_lds16(src,      dst);
        gload_lds16(src + 16, dst + 1024);
      }
    }
  };

  float S[4][4];
#pragma unroll
  for (int rf = 0; rf < 4; ++rf)
#pragma unroll
    for (int r = 0; r < 4; ++r) S[rf][r] = 0.f;

  f32x4 acc[4][4];   // [row-frag][col-frag]; C=0 at each tile's ks0

  // per-phase compute: 2 ksteps, 4 col-frags (this wave's col-half), 4 row-frags
#define COMPUTE_PHASE(bufR, ksA, ksB, FIRSTF)                               \
  {                                                                         \
    __builtin_amdgcn_s_setprio(1);                                          \
    _Pragma("unroll")                                                       \
    for (int c = 0; c < 4; ++c) {                                           \
      const char* fb = (bufR) + (4 * ch + c) * 2048 + lane * 16;            \
      const i32x8 bf0 = frag32(fb);                                         \
      const i32x8 bf1 = frag32(fb + 16384);                                 \
      _Pragma("unroll")                                                     \
      for (int rf = 0; rf < 4; ++rf) {                                      \
        acc[rf][c] = __builtin_amdgcn_mfma_scale_f32_16x16x128_f8f6f4(      \
            Aa[rf][ksA], bf0,                                               \
            (FIRSTF) ? (f32x4){0.f, 0.f, 0.f, 0.f} : acc[rf][c],            \
            0, 0, 0, 127, 0, 122);                                          \
        acc[rf][c] = __builtin_amdgcn_mfma_scale_f32_16x16x128_f8f6f4(      \
            Aa[rf][ksB], bf1, acc[rf][c], 0, 0, 0, 127, 0, 122);            \
      }                                                                     \
    }                                                                       \
    __builtin_amdgcn_s_setprio(0);                                          \
  }

  auto epilogue = [&](int ti) {
    // C/D (16x16): col = (t0+ti)*128 + 64ch + 16c + fr, row = m0+64rh+16rf+4fq+r
    const float* bT = &ldsBias[ti * 128 + 64 * ch];
    float badd[4];
#pragma unroll
    for (int c = 0; c < 4; ++c) badd[c] = bT[16 * c + fr];
#pragma unroll
    for (int rf = 0; rf < 4; ++rf)
#pragma unroll
      for (int r = 0; r < 4; ++r) {
        float sum = 0.f;
#pragma unroll
        for (int c = 0; c < 4; ++c)
          sum += __builtin_amdgcn_exp2f(acc[rf][c][r] + badd[c]);
        S[rf][r] += sum;
      }
  };

  const char* wt = wb + (size_t)t0 * TILEB;
  stagePhase(wt, 0, ldsB[0]);     // prologue: tile t0 phase 0 in flight

  for (int tt = t0; tt < t1; ++tt, wt += TILEB) {
    // phase 0 (ks 0,1) in buf0; stage phase 1 -> buf1
    WAITV0(); BARRIER_PIN();
    stagePhase(wt, 1, ldsB[1]);
    __builtin_amdgcn_sched_barrier(0);
    COMPUTE_PHASE(ldsB[0], 0, 1, true)

    // phase 1 (ks 2,3) in buf1; stage next tile phase 0 -> buf0
    WAITV0(); BARRIER_PIN();
    if (tt + 1 < t1) stagePhase(wt + TILEB, 0, ldsB[0]);
    __builtin_amdgcn_sched_barrier(0);
    COMPUTE_PHASE(ldsB[1], 2, 3, false)

    epilogue(tt - t0);   // overlaps the in-flight next-tile stage
  }

  // ---- cross-wave (col-half) reduction: ch=1 dumps S, ch=0 accumulates ----
  __syncthreads();                       // ldsB free for scratch after this
  float* sc = (float*)ldsB;              // stride 20 floats: bank-spread, x4-aligned
  if (ch == 1) {
    float* base = sc + (size_t)(rh * 64 + lane) * 20;
#pragma unroll
    for (int rf = 0; rf < 4; ++rf)
      *(float4*)(base + rf * 4) = (float4){S[rf][0], S[rf][1], S[rf][2], S[rf][3]};
  }
  __syncthreads();
  if (ch == 0) {
    const float* base = sc + (size_t)(rh * 64 + lane) * 20;
#pragma unroll
    for (int rf = 0; rf < 4; ++rf) {
      const float4 v = *(const float4*)(base + rf * 4);
      S[rf][0] += v.x; S[rf][1] += v.y; S[rf][2] += v.z; S[rf][3] += v.w;
    }
    // reduce over the 16 fr-lanes sharing each row, write partials
#pragma unroll
    for (int rf = 0; rf < 4; ++rf)
#pragma unroll
      for (int r = 0; r < 4; ++r) {
        float v = S[rf][r];
        v += __shfl_xor(v, 1);
        v += __shfl_xor(v, 2);
        v += __shfl_xor(v, 4);
        v += __shfl_xor(v, 8);
        if (fr == 0) {
          const int row = m0 + 64 * rh + 16 * rf + 4 * fq + r;
          spart[(size_t)row * SPLITS + s] = v;
        }
      }
  }
#undef COMPUTE_PHASE
}

// ---------------- combine: loss = mean(log(sum_s S_part) - tgt), single block ----------------

__global__ __launch_bounds__(256) void combine_kernel(const float* __restrict__ spart,
                                                      const float* __restrict__ tgt,
                                                      float* __restrict__ out) {
  __shared__ float red[256];
  float local = 0.f;
  for (int r = threadIdx.x; r < N_ROWS; r += 256) {
    const float4* sp = (const float4*)(spart + (size_t)r * SPLITS);
    float st = 0.f;
#pragma unroll
    for (int i = 0; i < 8; ++i) { float4 v = sp[i]; st += (v.x + v.y) + (v.z + v.w); }
    local += __logf(st) - tgt[r];
  }
  red[threadIdx.x] = local;
  __syncthreads();
  for (int step = 128; step; step >>= 1) {
    if (threadIdx.x < step) red[threadIdx.x] += red[threadIdx.x + step];
    __syncthreads();
  }
  if (threadIdx.x == 0) out[0] = red[0] * (1.0f / (float)N_ROWS);
}

// ---------------- launch ----------------
// ws: x_fp8 [4096][512]B @0 | W_fp8 [100096][512]B | S_part [4096][32] f32 | tgt [4096] f32

extern "C" void kernel_launch(void* const* d_in, const int* in_sizes, int n_in,
                              void* d_out, int out_size, void* d_ws, size_t ws_size,
                              hipStream_t stream) {
  const float* x  = (const float*)d_in[0];
  const int*   lb = (const int*)d_in[1];
  const float* W  = (const float*)d_in[2];
  const float* b  = (const float*)d_in[3];
  float* out = (float*)d_out;

  char* ws = (char*)d_ws;
  const size_t OFF_W   = (size_t)XELEMS;          // 2097152
  const size_t OFF_SP  = OFF_W + WBYTES;          // 53346304
  const size_t OFF_TGT = OFF_SP + (size_t)N_ROWS * SPLITS * 4;
  char*  xb    = ws;
  char*  wb    = ws + OFF_W;
  float* spart = (float*)(ws + OFF_SP);
  float* tgt   = (float*)(ws + OFF_TGT);

  cvt_kernel<<<13024, 256, 0, stream>>>(x, W, ws);
  tgt_kernel<<<1024, 256, 0, stream>>>(x, lb, W, b, tgt);
  lse_kernel<<<1024, 256, 0, stream>>>(xb, wb, b, spart);
  combine_kernel<<<1, 256, 0, stream>>>(spart, tgt, out);
}